// Round 7
// baseline (4839.655 us; speedup 1.0000x reference)
//
#include <hip/hip_runtime.h>
#include <hip/hip_fp16.h>
#include <cfloat>
#include <type_traits>

#define DEV __device__ __forceinline__

DEV int nt_loadi(const int* p) { return __builtin_nontemporal_load(p); }

DEV unsigned enc_ord(float f) {
    unsigned u = __float_as_uint(f);
    return (u & 0x80000000u) ? ~u : (u | 0x80000000u);
}

#define WSHIFT 14
#define WCAP 7
#define NWIN 8

// ================= bucketed CSR build =================
__global__ __launch_bounds__(256) void k_bcount(const int* __restrict__ dst, int* __restrict__ bcnt, int E) {
    __shared__ int hist[256];
    int tid = threadIdx.x;
    hist[tid] = 0;
    __syncthreads();
    int base = blockIdx.x * 4096;
#pragma unroll
    for (int j = 0; j < 16; ++j) {
        int e = base + j * 256 + tid;
        if (e < E) atomicAdd(&hist[dst[e] >> 9], 1);
    }
    __syncthreads();
    if (hist[tid]) atomicAdd(&bcnt[tid], hist[tid]);
}

__global__ __launch_bounds__(256) void k_bscan(const int* __restrict__ bcnt, int* __restrict__ bbase,
                                               int* __restrict__ bcur, int* __restrict__ rowptr,
                                               int nb, int n, int E) {
    __shared__ int sh[256];
    int tid = threadIdx.x;
    int v = (tid < nb) ? bcnt[tid] : 0;
    sh[tid] = v; __syncthreads();
    for (int off = 1; off < 256; off <<= 1) {
        int x = (tid >= off) ? sh[tid - off] : 0; __syncthreads();
        sh[tid] += x; __syncthreads();
    }
    int excl = sh[tid] - v;
    if (tid < nb) { bbase[tid] = excl; bcur[tid] = excl; }
    if (tid == 0) { bbase[nb] = E; rowptr[n] = E; }
}

__global__ __launch_bounds__(256) void k_bscatter(const int* __restrict__ ei, int* __restrict__ bcur,
                                                  int2* __restrict__ pairs, int E) {
    __shared__ int hist[256];
    __shared__ int gbase[256];
    int tid = threadIdx.x;
    hist[tid] = 0;
    __syncthreads();
    int base = blockIdx.x * 4096;
    int d[16], li[16];
#pragma unroll
    for (int j = 0; j < 16; ++j) {
        int e = base + j * 256 + tid;
        if (e < E) {
            d[j] = ei[E + e];
            li[j] = atomicAdd(&hist[d[j] >> 9], 1);
        }
    }
    __syncthreads();
    if (hist[tid]) gbase[tid] = atomicAdd(&bcur[tid], hist[tid]);
    __syncthreads();
#pragma unroll
    for (int j = 0; j < 16; ++j) {
        int e = base + j * 256 + tid;
        if (e < E) {
            int b = d[j] >> 9;
            pairs[gbase[b] + li[j]] = make_int2(ei[e], d[j]);
        }
    }
}

// Counting sort within dst-bucket keyed by (dst_local, src>>WSHIFT); also emits
// packed per-(row,window) u16 counts so the windowed agg needs no extra offsets.
__global__ __launch_bounds__(512) void k_bfill(const int2* __restrict__ pairs, const int* __restrict__ bbase,
                                               int* __restrict__ rowptr, float* __restrict__ dinv,
                                               int* __restrict__ colA, uint4* __restrict__ wcnt4, int n) {
    __shared__ int scnt[512 * NWIN];   // 16 KB
    __shared__ int sscan[512];
    int tid = threadIdx.x;
    int b = blockIdx.x;
    int bb = bbase[b], be = bbase[b + 1];
    int nodeBase = b << 9;
    for (int i = tid; i < 512 * NWIN; i += 512) scnt[i] = 0;
    __syncthreads();
    for (int e = bb + tid; e < be; e += 512) {
        int2 pr = pairs[e];
        int w = min(WCAP, pr.x >> WSHIFT);
        atomicAdd(&scnt[(pr.y & 511) * NWIN + w], 1);
    }
    __syncthreads();
    int base = tid * NWIN;
    int cnt[NWIN];
    int deg = 0;
#pragma unroll
    for (int w = 0; w < NWIN; ++w) { cnt[w] = scnt[base + w]; deg += cnt[w]; }
    sscan[tid] = deg;
    __syncthreads();
    for (int off = 1; off < 512; off <<= 1) {
        int x = (tid >= off) ? sscan[tid - off] : 0; __syncthreads();
        sscan[tid] += x; __syncthreads();
    }
    int excl = sscan[tid] - deg;
    int node = nodeBase + tid;
    if (node < n) {
        rowptr[node] = bb + excl;
        dinv[node] = rsqrtf((float)deg + 1.0f);  // +1 self loop
        uint4 pc;
        pc.x = (unsigned)cnt[0] | ((unsigned)cnt[1] << 16);
        pc.y = (unsigned)cnt[2] | ((unsigned)cnt[3] << 16);
        pc.z = (unsigned)cnt[4] | ((unsigned)cnt[5] << 16);
        pc.w = (unsigned)cnt[6] | ((unsigned)cnt[7] << 16);
        wcnt4[node] = pc;
    }
    int run = excl;
#pragma unroll
    for (int w = 0; w < NWIN; ++w) { int c = cnt[w]; scnt[base + w] = run; run += c; }
    __syncthreads();
    for (int e = bb + tid; e < be; e += 512) {
        int2 pr = pairs[e];
        int w = min(WCAP, pr.x >> WSHIFT);
        int p = atomicAdd(&scnt[(pr.y & 511) * NWIN + w], 1);
        colA[bb + p] = pr.x;
    }
}

// ================= dense matmul =================
template <int K, int COUT, bool SCALE, bool BIAS, typename TIN, typename TOUT>
__global__ __launch_bounds__(256) void k_mm(const TIN* __restrict__ in, const float* __restrict__ W,
                                            const float* __restrict__ bias, const float* __restrict__ dinv,
                                            TOUT* __restrict__ out, int n, int ldw, int ldo, int colOff) {
    constexpr int CG = COUT / 4;
    constexpr int SLOTS = 256 / CG;
    constexpr int TR = (K == 128) ? 32 : 64;
    constexpr int RPT = TR / SLOTS;
    constexpr int KP = K + 1;
    __shared__ __align__(16) float sW[K * COUT];
    __shared__ float sH[TR * KP];
    const int tid = threadIdx.x;
    const int rowBase = blockIdx.x * TR;

    constexpr int W4 = COUT / 4;
    for (int idx = tid; idx < K * W4; idx += 256) {
        int k = idx / W4, c4 = idx - k * W4;
        ((float4*)sW)[idx] = *(const float4*)(W + (size_t)k * ldw + colOff + c4 * 4);
    }
    if constexpr (std::is_same<TIN, float>::value) {
        const float4* inp4 = (const float4*)(in + (size_t)rowBase * K);
        for (int idx = tid; idx < TR * K / 4; idx += 256) {
            int elem = idx * 4;
            int r = elem / K, k = elem - r * K;
            float4 h = (rowBase + r < n) ? inp4[idx] : make_float4(0.f, 0.f, 0.f, 0.f);
            float* dd = &sH[r * KP + k];
            dd[0] = h.x; dd[1] = h.y; dd[2] = h.z; dd[3] = h.w;
        }
    } else {
        const uint4* inp8 = (const uint4*)(in + (size_t)rowBase * K);
        for (int idx = tid; idx < TR * K / 8; idx += 256) {
            int elem = idx * 8;
            int r = elem / K, k = elem - r * K;
            uint4 h = make_uint4(0u, 0u, 0u, 0u);
            if (rowBase + r < n) h = inp8[idx];
            const __half2* hh = (const __half2*)&h;
            float* dd = &sH[r * KP + k];
#pragma unroll
            for (int q = 0; q < 4; ++q) {
                float2 f = __half22float2(hh[q]);
                dd[2 * q] = f.x; dd[2 * q + 1] = f.y;
            }
        }
    }
    __syncthreads();

    const int cg_ = tid % CG;
    const int slot = tid / CG;
    float4 acc[RPT];
#pragma unroll
    for (int j = 0; j < RPT; ++j) acc[j] = make_float4(0.f, 0.f, 0.f, 0.f);
#pragma unroll 4
    for (int k = 0; k < K; ++k) {
        float4 w = *(const float4*)&sW[k * COUT + cg_ * 4];
#pragma unroll
        for (int j = 0; j < RPT; ++j) {
            float h = sH[(slot + j * SLOTS) * KP + k];
            acc[j].x += h * w.x; acc[j].y += h * w.y; acc[j].z += h * w.z; acc[j].w += h * w.w;
        }
    }
#pragma unroll
    for (int j = 0; j < RPT; ++j) {
        int r = rowBase + slot + j * SLOTS;
        if (r < n) {
            float4 o = acc[j];
            if (SCALE) { float di = dinv[r]; o.x *= di; o.y *= di; o.z *= di; o.w *= di; }
            if (BIAS) {
                float4 b = *(const float4*)(bias + colOff + cg_ * 4);
                o.x += b.x; o.y += b.y; o.z += b.z; o.w += b.w;
            }
            if constexpr (std::is_same<TOUT, float>::value) {
                *(float4*)(out + (size_t)r * ldo + colOff + cg_ * 4) = o;
            } else {
                __half2 p0 = __floats2half2_rn(o.x, o.y);
                __half2 p1 = __floats2half2_rn(o.z, o.w);
                uint2 st;
                st.x = *(unsigned*)&p0; st.y = *(unsigned*)&p1;
                *(uint2*)(out + (size_t)r * ldo + colOff + cg_ * 4) = st;
            }
        }
    }
}

// ================= windowed aggregation (soft barrier + branchless chains) =================
// r3's proven soft barrier (full 2-block/CU residency at 511 blocks held phasing:
// FETCH 165MB) combined with r5's proven branchless clamped gather chains (full
// memory-level parallelism). Barrier is perf-only (bounded spin, accumulators
// private) -> deadlock-impossible; correctness identical to r5.
// MODE 0: out=relu(di*s+b)  1: di*s+b  2: di*relu(di*s+b)  3: di^2*s  4: di*s
template <int MODE>
__global__ __launch_bounds__(256, 2) void k_wagg(
    const __half* __restrict__ g, const int* __restrict__ rowptr,
    const uint4* __restrict__ wcnt4, const int* __restrict__ col,
    const float* __restrict__ dinv, const float* __restrict__ bias,
    __half* __restrict__ out, int n, int E, int nwin, int ld, int off,
    unsigned* __restrict__ bar, int li) {
    constexpr int RPB = 196;             // rows per block (511 blocks * 196 >= 100000)
    constexpr int RPG = 7;               // row-chains per 8-lane group (32*7 >= 196)
    const int tid = threadIdx.x;
    const int gg = tid >> 3;
    const int sl = tid & 7;
    const int rb = blockIdx.x * RPB;
    const int Em1 = E - 1;
    const uint4* g4 = (const uint4*)g + off + sl;

    int rowv[RPG]; bool val[RPG]; int ecur[RPG];
    unsigned cw[RPG][4];
    float acc[RPG][8];
#pragma unroll
    for (int rr = 0; rr < RPG; ++rr) {
        int ro = gg + (rr << 5);
        int row = rb + ro;
        rowv[rr] = row;
        bool v = (ro < RPB) && (row < n);
        val[rr] = v;
        if (v) {
            ecur[rr] = rowptr[row];
            uint4 c4 = wcnt4[row];
            cw[rr][0] = c4.x; cw[rr][1] = c4.y; cw[rr][2] = c4.z; cw[rr][3] = c4.w;
            uint4 s = g4[(size_t)row * ld];  // self loop (cached: it IS the table)
            const __half2* h = (const __half2*)&s;
#pragma unroll
            for (int q = 0; q < 4; ++q) {
                float2 f = __half22float2(h[q]);
                acc[rr][2 * q] = f.x; acc[rr][2 * q + 1] = f.y;
            }
        } else {
            ecur[rr] = 0;
            cw[rr][0] = cw[rr][1] = cw[rr][2] = cw[rr][3] = 0u;
#pragma unroll
            for (int q = 0; q < 8; ++q) acc[rr][q] = 0.f;
        }
    }

#pragma unroll
    for (int w = 0; w < NWIN; ++w) {
        // dense L2 prefetch of this window's table slice (one touch per 128B line).
        // slice = (bid>>3)&63 assumes round-robin block->XCD dispatch; perf-only.
        {
            int wb = w << WSHIFT;
            int hi = min(n, wb + (1 << WSHIFT));
            int pr = wb + (((int)(blockIdx.x >> 3) & 63) << 8) + tid;
            if (pr < hi) {
                uint4 t = g4[(size_t)pr * ld];
                asm volatile("" :: "v"(t.x), "v"(t.y), "v"(t.z), "v"(t.w));
            }
        }
        // branchless windowed gather: clamp to segment end, mask the FMA
        int cnt[RPG], cm1[RPG], b0[RPG];
        int mx = 0;
#pragma unroll
        for (int rr = 0; rr < RPG; ++rr) {
            int c = (int)((cw[rr][w >> 1] >> ((w & 1) * 16)) & 0xffffu);
            cnt[rr] = c;
            cm1[rr] = max(c - 1, 0);
            b0[rr] = ecur[rr];
            ecur[rr] += c;
            mx = max(mx, c);
        }
        int ci[RPG];
#pragma unroll
        for (int rr = 0; rr < RPG; ++rr)
            ci[rr] = nt_loadi(&col[min(b0[rr], Em1)]);
        for (int s = 0; s < mx; ++s) {
            uint4 v[RPG];
#pragma unroll
            for (int rr = 0; rr < RPG; ++rr) v[rr] = g4[(size_t)ci[rr] * ld];
            int cn[RPG];
#pragma unroll
            for (int rr = 0; rr < RPG; ++rr)
                cn[rr] = nt_loadi(&col[min(b0[rr] + min(s + 1, cm1[rr]), Em1)]);
#pragma unroll
            for (int rr = 0; rr < RPG; ++rr) {
                float m = (s < cnt[rr]) ? 1.f : 0.f;
                const __half2* h = (const __half2*)&v[rr];
#pragma unroll
                for (int q = 0; q < 4; ++q) {
                    float2 f = __half22float2(h[q]);
                    acc[rr][2 * q]     = fmaf(m, f.x, acc[rr][2 * q]);
                    acc[rr][2 * q + 1] = fmaf(m, f.y, acc[rr][2 * q + 1]);
                }
                ci[rr] = cn[rr];
            }
        }
        if (w + 1 >= nwin) break;                  // remaining windows empty

        __syncthreads();                           // whole block done with window w
        if (tid == 0) {
            unsigned tgt = (unsigned)(w + 1) * gridDim.x;
            unsigned old = atomicAdd(&bar[li * 2], 1u);
            if (old + 1 == tgt) {
                __hip_atomic_store(&bar[li * 2 + 1], (unsigned)(w + 1),
                                   __ATOMIC_RELEASE, __HIP_MEMORY_SCOPE_AGENT);
            } else {
                int spins = 0;
                while (__hip_atomic_load(&bar[li * 2 + 1], __ATOMIC_ACQUIRE,
                                         __HIP_MEMORY_SCOPE_AGENT) < (unsigned)(w + 1) &&
                       ++spins < 3000)
                    __builtin_amdgcn_s_sleep(4);
            }
        }
        __syncthreads();
    }

    float4 bb0, bb1;
    if (MODE == 0 || MODE == 1 || MODE == 2) {
        bb0 = *(const float4*)(bias + off * 8 + sl * 8);
        bb1 = *(const float4*)(bias + off * 8 + sl * 8 + 4);
    }
#pragma unroll
    for (int rr = 0; rr < RPG; ++rr) {
        if (!val[rr]) continue;
        int row = rowv[rr];
        float di = dinv[row];
        float r8[8];
        if (MODE == 0 || MODE == 1 || MODE == 2) {
            float bb[8] = {bb0.x, bb0.y, bb0.z, bb0.w, bb1.x, bb1.y, bb1.z, bb1.w};
#pragma unroll
            for (int t = 0; t < 8; ++t) {
                float s = di * acc[rr][t] + bb[t];
                if (MODE == 0) r8[t] = fmaxf(s, 0.f);
                else if (MODE == 1) r8[t] = s;
                else r8[t] = di * fmaxf(s, 0.f);
            }
        } else if (MODE == 3) {
            float d2 = di * di;
#pragma unroll
            for (int t = 0; t < 8; ++t) r8[t] = acc[rr][t] * d2;
        } else {
#pragma unroll
            for (int t = 0; t < 8; ++t) r8[t] = acc[rr][t] * di;
        }
        uint4 o;
        __half2* oh = (__half2*)&o;
#pragma unroll
        for (int q = 0; q < 4; ++q) oh[q] = __floats2half2_rn(r8[2 * q], r8[2 * q + 1]);
        *((uint4*)out + (size_t)row * ld + off + sl) = o;
    }
}

// ================= global max pool (batch sorted) =================
__global__ __launch_bounds__(64) void k_pool(const float* __restrict__ z, const int* __restrict__ batch,
                                             unsigned* __restrict__ pooled, int n) {
    constexpr int ROWS = 128;
    int lane = threadIdx.x;
    int r0 = blockIdx.x * ROWS;
    if (r0 >= n) return;
    int r1 = min(r0 + ROWS, n);
    int cur = batch[r0];
    float m = -FLT_MAX;
    for (int r = r0; r < r1; ++r) {
        int b = batch[r];
        float v = z[(size_t)r * 64 + lane];
        if (b != cur) {
            atomicMax(&pooled[cur * 64 + lane], enc_ord(m));
            cur = b; m = v;
        } else {
            m = fmaxf(m, v);
        }
    }
    atomicMax(&pooled[cur * 64 + lane], enc_ord(m));
}

// ================= final MLP =================
__global__ __launch_bounds__(256) void k_mlp(const unsigned* __restrict__ pooled,
                                             const float* __restrict__ fc1w, const float* __restrict__ fc1b,
                                             const float* __restrict__ fc2w, const float* __restrict__ fc2b,
                                             const float* __restrict__ cpdw, const float* __restrict__ cpdb,
                                             const float* __restrict__ combw, const float* __restrict__ combb,
                                             float* __restrict__ out, int G) {
    __shared__ float s1[64 * 32], s2[32 * 16], sb1[32], sb2[16], scw[16], sow[16], shead[2];
    int tid = threadIdx.x;
    for (int i = tid; i < 2048; i += 256) s1[i] = fc1w[i];
    for (int i = tid; i < 512; i += 256) s2[i] = fc2w[i];
    if (tid < 32) sb1[tid] = fc1b[tid];
    if (tid < 16) { sb2[tid] = fc2b[tid]; scw[tid] = cpdw[tid]; sow[tid] = combw[tid]; }
    if (tid == 0) { shead[0] = cpdb[0]; shead[1] = combb[0]; }
    __syncthreads();
    if (tid < G) {
        float h0[64];
#pragma unroll
        for (int k = 0; k < 64; ++k) {
            unsigned u = pooled[tid * 64 + k];
            unsigned b = (u & 0x80000000u) ? (u & 0x7fffffffu) : ~u;
            h0[k] = __uint_as_float(b);
        }
        float h1[32];
#pragma unroll
        for (int j = 0; j < 32; ++j) {
            float a = sb1[j];
#pragma unroll
            for (int k = 0; k < 64; ++k) a += h0[k] * s1[k * 32 + j];
            h1[j] = fmaxf(a, 0.f);
        }
        float h2[16];
#pragma unroll
        for (int j = 0; j < 16; ++j) {
            float a = sb2[j];
#pragma unroll
            for (int k = 0; k < 32; ++k) a += h1[k] * s2[k * 16 + j];
            h2[j] = fmaxf(a, 0.f);
        }
        float c1 = shead[0], c2 = shead[1];
#pragma unroll
        for (int k = 0; k < 16; ++k) { c1 += h2[k] * scw[k]; c2 += h2[k] * sow[k]; }
        out[tid] = c1;
        out[G + tid] = c2;
    }
}

extern "C" void kernel_launch(void* const* d_in, const int* in_sizes, int n_in,
                              void* d_out, int out_size, void* d_ws, size_t ws_size,
                              hipStream_t stream) {
    const float* x      = (const float*)d_in[0];
    const int*   ei     = (const int*)d_in[1];
    const int*   batch  = (const int*)d_in[2];
    const float* enc_w1 = (const float*)d_in[3];
    const float* enc_b1 = (const float*)d_in[4];
    const float* enc_w2 = (const float*)d_in[5];
    const float* enc_b2 = (const float*)d_in[6];
    const float* w1 = (const float*)d_in[7];   const float* b1 = (const float*)d_in[8];
    const float* w2 = (const float*)d_in[9];   const float* b2 = (const float*)d_in[10];
    const float* w3 = (const float*)d_in[11];  const float* b3 = (const float*)d_in[12];
    const float* sgw = (const float*)d_in[13]; const float* sgb = (const float*)d_in[14];
    const float* fc1w = (const float*)d_in[15]; const float* fc1b = (const float*)d_in[16];
    const float* fc2w = (const float*)d_in[17]; const float* fc2b = (const float*)d_in[18];
    const float* cpdw = (const float*)d_in[19]; const float* cpdb = (const float*)d_in[20];
    const float* combw = (const float*)d_in[21]; const float* combb = (const float*)d_in[22];

    const int n = in_sizes[0] / 128;
    const int E = in_sizes[1] / 2;
    const int G = out_size / 2;
    const int nb = (n + 511) >> 9;
    float* outp = (float*)d_out;

    char* p = (char*)d_ws;
    auto alloc = [&](size_t bytes) -> char* {
        char* r = p;
        p += (bytes + 255) & ~(size_t)255;
        return r;
    };
    int* rowptr      = (int*)alloc((size_t)(n + 1) * 4);
    float* dinv      = (float*)alloc((size_t)n * 4);
    int* bcnt        = (int*)alloc(256 * 4);
    int* bbase       = (int*)alloc(257 * 4);
    int* bcur        = (int*)alloc(256 * 4);
    int* colA        = (int*)alloc((size_t)E * 4);
    unsigned* pooled = (unsigned*)alloc((size_t)G * 64 * 4);
    __half* A        = (__half*)alloc((size_t)n * 128 * 4);  // oversized: aliases pairs (E*8 bytes)
    __half* B        = (__half*)alloc((size_t)n * 128 * 2);
    float* Cf        = (float*)alloc((size_t)n * 64 * 4);
    uint4* wcnt4     = (uint4*)alloc((size_t)n * 16);
    unsigned* bar    = (unsigned*)alloc(64 * 4);
    int2* pairs      = (int2*)A;  // alias: pairs dead before first k_mm writes A

    hipMemsetAsync(bcnt, 0, 256 * 4, stream);
    hipMemsetAsync(pooled, 0, (size_t)G * 64 * 4, stream);
    hipMemsetAsync(bar, 0, 64 * 4, stream);

    const int gE = (E + 4095) / 4096;
    k_bcount<<<gE, 256, 0, stream>>>(ei + E, bcnt, E);
    k_bscan<<<1, 256, 0, stream>>>(bcnt, bbase, bcur, rowptr, nb, n, E);
    k_bscatter<<<gE, 256, 0, stream>>>(ei, bcur, pairs, E);
    k_bfill<<<nb, 512, 0, stream>>>(pairs, bbase, rowptr, dinv, colA, wcnt4, n);

    const int gm128 = (n + 31) / 32;
    const int gm64  = (n + 63) / 64;
    const int gw    = (n + 195) / 196;             // 511 blocks @ 2/CU: proven resident (r3)
    const int nwin  = (n + (1 << WSHIFT) - 1) >> WSHIFT;

    // encoder layer 1: x fp32 -> A fp16 (two column halves), windowed propagate+relu
    k_mm<128, 64, true, false, float, __half><<<gm128, 256, 0, stream>>>(x, enc_w1, nullptr, dinv, A, n, 128, 128, 0);
    k_mm<128, 64, true, false, float, __half><<<gm128, 256, 0, stream>>>(x, enc_w1, nullptr, dinv, A, n, 128, 128, 64);
    k_wagg<0><<<gw, 256, 0, stream>>>(A, rowptr, wcnt4, colA, dinv, enc_b1, B, n, E, nwin, 16, 0, bar, 0);
    k_wagg<0><<<gw, 256, 0, stream>>>(A, rowptr, wcnt4, colA, dinv, enc_b1, B, n, E, nwin, 16, 8, bar, 1);
    // encoder layer 2: [N,128] fp16 -> [N,64] fp16
    k_mm<128, 64, true, false, __half, __half><<<gm128, 256, 0, stream>>>(B, enc_w2, nullptr, dinv, A, n, 64, 64, 0);
    k_wagg<1><<<gw, 256, 0, stream>>>(A, rowptr, wcnt4, colA, dinv, enc_b2, B, n, E, nwin, 8, 0, bar, 2);
    // conv1, conv2
    k_mm<64, 64, true, false, __half, __half><<<gm64, 256, 0, stream>>>(B, w1, nullptr, dinv, A, n, 64, 64, 0);
    k_wagg<0><<<gw, 256, 0, stream>>>(A, rowptr, wcnt4, colA, dinv, b1, B, n, E, nwin, 8, 0, bar, 3);
    k_mm<64, 64, true, false, __half, __half><<<gm64, 256, 0, stream>>>(B, w2, nullptr, dinv, A, n, 64, 64, 0);
    k_wagg<0><<<gw, 256, 0, stream>>>(A, rowptr, wcnt4, colA, dinv, b2, B, n, E, nwin, 8, 0, bar, 4);
    // conv3 (output pre-scaled by dinv for SG chain)
    k_mm<64, 64, true, false, __half, __half><<<gm64, 256, 0, stream>>>(B, w3, nullptr, dinv, A, n, 64, 64, 0);
    k_wagg<2><<<gw, 256, 0, stream>>>(A, rowptr, wcnt4, colA, dinv, b3, B, n, E, nwin, 8, 0, bar, 5);
    // SGConv K=4 propagates
    k_wagg<3><<<gw, 256, 0, stream>>>(B, rowptr, wcnt4, colA, dinv, b3, A, n, E, nwin, 8, 0, bar, 6);
    k_wagg<3><<<gw, 256, 0, stream>>>(A, rowptr, wcnt4, colA, dinv, b3, B, n, E, nwin, 8, 0, bar, 7);
    k_wagg<3><<<gw, 256, 0, stream>>>(B, rowptr, wcnt4, colA, dinv, b3, A, n, E, nwin, 8, 0, bar, 8);
    k_wagg<4><<<gw, 256, 0, stream>>>(A, rowptr, wcnt4, colA, dinv, b3, B, n, E, nwin, 8, 0, bar, 9);
    // SG linear -> fp32 for pool
    k_mm<64, 64, false, true, __half, float><<<gm64, 256, 0, stream>>>(B, sgw, sgb, dinv, Cf, n, 64, 64, 0);
    // pool + heads
    k_pool<<<(n + 127) / 128, 64, 0, stream>>>(Cf, batch, pooled, n);
    k_mlp<<<1, 256, 0, stream>>>(pooled, fc1w, fc1b, fc2w, fc2b, cpdw, cpdb, combw, combb, outp, G);
}

// Round 8
// 4705.293 us; speedup vs baseline: 1.0286x; 1.0286x over previous
//
#include <hip/hip_runtime.h>
#include <hip/hip_fp16.h>
#include <cfloat>
#include <type_traits>

#define DEV __device__ __forceinline__

DEV int nt_loadi(const int* p) { return __builtin_nontemporal_load(p); }

DEV unsigned enc_ord(float f) {
    unsigned u = __float_as_uint(f);
    return (u & 0x80000000u) ? ~u : (u | 0x80000000u);
}

#define WSHIFT 14
#define WCAP 7
#define NWIN 8

// ================= bucketed CSR build =================
__global__ __launch_bounds__(256) void k_bcount(const int* __restrict__ dst, int* __restrict__ bcnt, int E) {
    __shared__ int hist[256];
    int tid = threadIdx.x;
    hist[tid] = 0;
    __syncthreads();
    int base = blockIdx.x * 4096;
#pragma unroll
    for (int j = 0; j < 16; ++j) {
        int e = base + j * 256 + tid;
        if (e < E) atomicAdd(&hist[dst[e] >> 9], 1);
    }
    __syncthreads();
    if (hist[tid]) atomicAdd(&bcnt[tid], hist[tid]);
}

__global__ __launch_bounds__(256) void k_bscan(const int* __restrict__ bcnt, int* __restrict__ bbase,
                                               int* __restrict__ bcur, int* __restrict__ rowptr,
                                               int nb, int n, int E) {
    __shared__ int sh[256];
    int tid = threadIdx.x;
    int v = (tid < nb) ? bcnt[tid] : 0;
    sh[tid] = v; __syncthreads();
    for (int off = 1; off < 256; off <<= 1) {
        int x = (tid >= off) ? sh[tid - off] : 0; __syncthreads();
        sh[tid] += x; __syncthreads();
    }
    int excl = sh[tid] - v;
    if (tid < nb) { bbase[tid] = excl; bcur[tid] = excl; }
    if (tid == 0) { bbase[nb] = E; rowptr[n] = E; }
}

__global__ __launch_bounds__(256) void k_bscatter(const int* __restrict__ ei, int* __restrict__ bcur,
                                                  int2* __restrict__ pairs, int E) {
    __shared__ int hist[256];
    __shared__ int gbase[256];
    int tid = threadIdx.x;
    hist[tid] = 0;
    __syncthreads();
    int base = blockIdx.x * 4096;
    int d[16], li[16];
#pragma unroll
    for (int j = 0; j < 16; ++j) {
        int e = base + j * 256 + tid;
        if (e < E) {
            d[j] = ei[E + e];
            li[j] = atomicAdd(&hist[d[j] >> 9], 1);
        }
    }
    __syncthreads();
    if (hist[tid]) gbase[tid] = atomicAdd(&bcur[tid], hist[tid]);
    __syncthreads();
#pragma unroll
    for (int j = 0; j < 16; ++j) {
        int e = base + j * 256 + tid;
        if (e < E) {
            int b = d[j] >> 9;
            pairs[gbase[b] + li[j]] = make_int2(ei[e], d[j]);
        }
    }
}

// Counting sort within dst-bucket keyed by (dst_local, src>>WSHIFT); also emits
// packed per-(row,window) u16 counts so the windowed agg needs no extra offsets.
__global__ __launch_bounds__(512) void k_bfill(const int2* __restrict__ pairs, const int* __restrict__ bbase,
                                               int* __restrict__ rowptr, float* __restrict__ dinv,
                                               int* __restrict__ colA, uint4* __restrict__ wcnt4, int n) {
    __shared__ int scnt[512 * NWIN];   // 16 KB
    __shared__ int sscan[512];
    int tid = threadIdx.x;
    int b = blockIdx.x;
    int bb = bbase[b], be = bbase[b + 1];
    int nodeBase = b << 9;
    for (int i = tid; i < 512 * NWIN; i += 512) scnt[i] = 0;
    __syncthreads();
    for (int e = bb + tid; e < be; e += 512) {
        int2 pr = pairs[e];
        int w = min(WCAP, pr.x >> WSHIFT);
        atomicAdd(&scnt[(pr.y & 511) * NWIN + w], 1);
    }
    __syncthreads();
    int base = tid * NWIN;
    int cnt[NWIN];
    int deg = 0;
#pragma unroll
    for (int w = 0; w < NWIN; ++w) { cnt[w] = scnt[base + w]; deg += cnt[w]; }
    sscan[tid] = deg;
    __syncthreads();
    for (int off = 1; off < 512; off <<= 1) {
        int x = (tid >= off) ? sscan[tid - off] : 0; __syncthreads();
        sscan[tid] += x; __syncthreads();
    }
    int excl = sscan[tid] - deg;
    int node = nodeBase + tid;
    if (node < n) {
        rowptr[node] = bb + excl;
        dinv[node] = rsqrtf((float)deg + 1.0f);  // +1 self loop
        uint4 pc;
        pc.x = (unsigned)cnt[0] | ((unsigned)cnt[1] << 16);
        pc.y = (unsigned)cnt[2] | ((unsigned)cnt[3] << 16);
        pc.z = (unsigned)cnt[4] | ((unsigned)cnt[5] << 16);
        pc.w = (unsigned)cnt[6] | ((unsigned)cnt[7] << 16);
        wcnt4[node] = pc;
    }
    int run = excl;
#pragma unroll
    for (int w = 0; w < NWIN; ++w) { int c = cnt[w]; scnt[base + w] = run; run += c; }
    __syncthreads();
    for (int e = bb + tid; e < be; e += 512) {
        int2 pr = pairs[e];
        int w = min(WCAP, pr.x >> WSHIFT);
        int p = atomicAdd(&scnt[(pr.y & 511) * NWIN + w], 1);
        colA[bb + p] = pr.x;
    }
}

// ================= dense matmul =================
template <int K, int COUT, bool SCALE, bool BIAS, typename TIN, typename TOUT>
__global__ __launch_bounds__(256) void k_mm(const TIN* __restrict__ in, const float* __restrict__ W,
                                            const float* __restrict__ bias, const float* __restrict__ dinv,
                                            TOUT* __restrict__ out, int n, int ldw, int ldo, int colOff) {
    constexpr int CG = COUT / 4;
    constexpr int SLOTS = 256 / CG;
    constexpr int TR = (K == 128) ? 32 : 64;
    constexpr int RPT = TR / SLOTS;
    constexpr int KP = K + 1;
    __shared__ __align__(16) float sW[K * COUT];
    __shared__ float sH[TR * KP];
    const int tid = threadIdx.x;
    const int rowBase = blockIdx.x * TR;

    constexpr int W4 = COUT / 4;
    for (int idx = tid; idx < K * W4; idx += 256) {
        int k = idx / W4, c4 = idx - k * W4;
        ((float4*)sW)[idx] = *(const float4*)(W + (size_t)k * ldw + colOff + c4 * 4);
    }
    if constexpr (std::is_same<TIN, float>::value) {
        const float4* inp4 = (const float4*)(in + (size_t)rowBase * K);
        for (int idx = tid; idx < TR * K / 4; idx += 256) {
            int elem = idx * 4;
            int r = elem / K, k = elem - r * K;
            float4 h = (rowBase + r < n) ? inp4[idx] : make_float4(0.f, 0.f, 0.f, 0.f);
            float* dd = &sH[r * KP + k];
            dd[0] = h.x; dd[1] = h.y; dd[2] = h.z; dd[3] = h.w;
        }
    } else {
        const uint4* inp8 = (const uint4*)(in + (size_t)rowBase * K);
        for (int idx = tid; idx < TR * K / 8; idx += 256) {
            int elem = idx * 8;
            int r = elem / K, k = elem - r * K;
            uint4 h = make_uint4(0u, 0u, 0u, 0u);
            if (rowBase + r < n) h = inp8[idx];
            const __half2* hh = (const __half2*)&h;
            float* dd = &sH[r * KP + k];
#pragma unroll
            for (int q = 0; q < 4; ++q) {
                float2 f = __half22float2(hh[q]);
                dd[2 * q] = f.x; dd[2 * q + 1] = f.y;
            }
        }
    }
    __syncthreads();

    const int cg_ = tid % CG;
    const int slot = tid / CG;
    float4 acc[RPT];
#pragma unroll
    for (int j = 0; j < RPT; ++j) acc[j] = make_float4(0.f, 0.f, 0.f, 0.f);
#pragma unroll 4
    for (int k = 0; k < K; ++k) {
        float4 w = *(const float4*)&sW[k * COUT + cg_ * 4];
#pragma unroll
        for (int j = 0; j < RPT; ++j) {
            float h = sH[(slot + j * SLOTS) * KP + k];
            acc[j].x += h * w.x; acc[j].y += h * w.y; acc[j].z += h * w.z; acc[j].w += h * w.w;
        }
    }
#pragma unroll
    for (int j = 0; j < RPT; ++j) {
        int r = rowBase + slot + j * SLOTS;
        if (r < n) {
            float4 o = acc[j];
            if (SCALE) { float di = dinv[r]; o.x *= di; o.y *= di; o.z *= di; o.w *= di; }
            if (BIAS) {
                float4 b = *(const float4*)(bias + colOff + cg_ * 4);
                o.x += b.x; o.y += b.y; o.z += b.z; o.w += b.w;
            }
            if constexpr (std::is_same<TOUT, float>::value) {
                *(float4*)(out + (size_t)r * ldo + colOff + cg_ * 4) = o;
            } else {
                __half2 p0 = __floats2half2_rn(o.x, o.y);
                __half2 p1 = __floats2half2_rn(o.z, o.w);
                uint2 st;
                st.x = *(unsigned*)&p0; st.y = *(unsigned*)&p1;
                *(uint2*)(out + (size_t)r * ldo + colOff + cg_ * 4) = st;
            }
        }
    }
}

// ================= windowed aggregation (per-window barrier + branchless chains) =====
// Soft grid barrier with PER-WINDOW counters/flags: each block increments window
// w's counter exactly once; the gridDim-th arrival sets flag[w] unconditionally.
// No cross-phase counter pollution; a timeout cannot cascade (flag still gets set,
// stragglers exit instantly). Barrier is perf-only; accumulators private.
// MODE 0: out=relu(di*s+b)  1: di*s+b  2: di*relu(di*s+b)  3: di^2*s  4: di*s
template <int MODE>
__global__ __launch_bounds__(256, 2) void k_wagg(
    const __half* __restrict__ g, const int* __restrict__ rowptr,
    const uint4* __restrict__ wcnt4, const int* __restrict__ col,
    const float* __restrict__ dinv, const float* __restrict__ bias,
    __half* __restrict__ out, int n, int E, int nwin, int ld, int off,
    unsigned* __restrict__ bar, int li) {
    constexpr int RPB = 196;             // rows per block (511 blocks * 196 >= 100000)
    constexpr int RPG = 7;               // row-chains per 8-lane group (32*7 >= 196)
    const int tid = threadIdx.x;
    const int gg = tid >> 3;
    const int sl = tid & 7;
    const int rb = blockIdx.x * RPB;
    const int Em1 = E - 1;
    const uint4* g4 = (const uint4*)g + off + sl;
    unsigned* cntw = bar + li * 16;       // [8] arrival counters (per window)
    unsigned* flgw = bar + li * 16 + 8;   // [8] release flags   (per window)

    int rowv[RPG]; bool val[RPG]; int ecur[RPG];
    unsigned cw[RPG][4];
    float acc[RPG][8];
#pragma unroll
    for (int rr = 0; rr < RPG; ++rr) {
        int ro = gg + (rr << 5);
        int row = rb + ro;
        rowv[rr] = row;
        bool v = (ro < RPB) && (row < n);
        val[rr] = v;
        if (v) {
            ecur[rr] = rowptr[row];
            uint4 c4 = wcnt4[row];
            cw[rr][0] = c4.x; cw[rr][1] = c4.y; cw[rr][2] = c4.z; cw[rr][3] = c4.w;
            uint4 s = g4[(size_t)row * ld];  // self loop (cached: it IS the table)
            const __half2* h = (const __half2*)&s;
#pragma unroll
            for (int q = 0; q < 4; ++q) {
                float2 f = __half22float2(h[q]);
                acc[rr][2 * q] = f.x; acc[rr][2 * q + 1] = f.y;
            }
        } else {
            ecur[rr] = 0;
            cw[rr][0] = cw[rr][1] = cw[rr][2] = cw[rr][3] = 0u;
#pragma unroll
            for (int q = 0; q < 8; ++q) acc[rr][q] = 0.f;
        }
    }

#pragma unroll
    for (int w = 0; w < NWIN; ++w) {
        // dense L2 prefetch of this window's table slice (one touch per 128B line).
        // slice = (bid>>3)&63 assumes round-robin block->XCD dispatch; perf-only.
        {
            int wb = w << WSHIFT;
            int hi = min(n, wb + (1 << WSHIFT));
            int pr = wb + (((int)(blockIdx.x >> 3) & 63) << 8) + tid;
            if (pr < hi) {
                uint4 t = g4[(size_t)pr * ld];
                asm volatile("" :: "v"(t.x), "v"(t.y), "v"(t.z), "v"(t.w));
            }
        }
        // branchless windowed gather: clamp to segment end, mask the FMA
        int cnt[RPG], cm1[RPG], b0[RPG];
        int mx = 0;
#pragma unroll
        for (int rr = 0; rr < RPG; ++rr) {
            int c = (int)((cw[rr][w >> 1] >> ((w & 1) * 16)) & 0xffffu);
            cnt[rr] = c;
            cm1[rr] = max(c - 1, 0);
            b0[rr] = ecur[rr];
            ecur[rr] += c;
            mx = max(mx, c);
        }
        int ci[RPG];
#pragma unroll
        for (int rr = 0; rr < RPG; ++rr)
            ci[rr] = nt_loadi(&col[min(b0[rr], Em1)]);
        for (int s = 0; s < mx; ++s) {
            uint4 v[RPG];
#pragma unroll
            for (int rr = 0; rr < RPG; ++rr) v[rr] = g4[(size_t)ci[rr] * ld];
            int cn[RPG];
#pragma unroll
            for (int rr = 0; rr < RPG; ++rr)
                cn[rr] = nt_loadi(&col[min(b0[rr] + min(s + 1, cm1[rr]), Em1)]);
#pragma unroll
            for (int rr = 0; rr < RPG; ++rr) {
                float m = (s < cnt[rr]) ? 1.f : 0.f;
                const __half2* h = (const __half2*)&v[rr];
#pragma unroll
                for (int q = 0; q < 4; ++q) {
                    float2 f = __half22float2(h[q]);
                    acc[rr][2 * q]     = fmaf(m, f.x, acc[rr][2 * q]);
                    acc[rr][2 * q + 1] = fmaf(m, f.y, acc[rr][2 * q + 1]);
                }
                ci[rr] = cn[rr];
            }
        }
        if (w + 1 >= nwin) break;                  // remaining windows empty

        __syncthreads();                           // whole block done with window w
        if (tid == 0) {
            unsigned old = atomicAdd(&cntw[w], 1u);
            if (old + 1 == gridDim.x) {
                __hip_atomic_store(&flgw[w], 1u, __ATOMIC_RELEASE, __HIP_MEMORY_SCOPE_AGENT);
            } else {
                int spins = 0;
                while (__hip_atomic_load(&flgw[w], __ATOMIC_ACQUIRE,
                                         __HIP_MEMORY_SCOPE_AGENT) == 0u &&
                       ++spins < 4000)
                    __builtin_amdgcn_s_sleep(2);
            }
        }
        __syncthreads();
    }

    float4 bb0, bb1;
    if (MODE == 0 || MODE == 1 || MODE == 2) {
        bb0 = *(const float4*)(bias + off * 8 + sl * 8);
        bb1 = *(const float4*)(bias + off * 8 + sl * 8 + 4);
    }
#pragma unroll
    for (int rr = 0; rr < RPG; ++rr) {
        if (!val[rr]) continue;
        int row = rowv[rr];
        float di = dinv[row];
        float r8[8];
        if (MODE == 0 || MODE == 1 || MODE == 2) {
            float bb[8] = {bb0.x, bb0.y, bb0.z, bb0.w, bb1.x, bb1.y, bb1.z, bb1.w};
#pragma unroll
            for (int t = 0; t < 8; ++t) {
                float s = di * acc[rr][t] + bb[t];
                if (MODE == 0) r8[t] = fmaxf(s, 0.f);
                else if (MODE == 1) r8[t] = s;
                else r8[t] = di * fmaxf(s, 0.f);
            }
        } else if (MODE == 3) {
            float d2 = di * di;
#pragma unroll
            for (int t = 0; t < 8; ++t) r8[t] = acc[rr][t] * d2;
        } else {
#pragma unroll
            for (int t = 0; t < 8; ++t) r8[t] = acc[rr][t] * di;
        }
        uint4 o;
        __half2* oh = (__half2*)&o;
#pragma unroll
        for (int q = 0; q < 4; ++q) oh[q] = __floats2half2_rn(r8[2 * q], r8[2 * q + 1]);
        *((uint4*)out + (size_t)row * ld + off + sl) = o;
    }
}

// ================= global max pool (batch sorted) =================
__global__ __launch_bounds__(64) void k_pool(const float* __restrict__ z, const int* __restrict__ batch,
                                             unsigned* __restrict__ pooled, int n) {
    constexpr int ROWS = 128;
    int lane = threadIdx.x;
    int r0 = blockIdx.x * ROWS;
    if (r0 >= n) return;
    int r1 = min(r0 + ROWS, n);
    int cur = batch[r0];
    float m = -FLT_MAX;
    for (int r = r0; r < r1; ++r) {
        int b = batch[r];
        float v = z[(size_t)r * 64 + lane];
        if (b != cur) {
            atomicMax(&pooled[cur * 64 + lane], enc_ord(m));
            cur = b; m = v;
        } else {
            m = fmaxf(m, v);
        }
    }
    atomicMax(&pooled[cur * 64 + lane], enc_ord(m));
}

// ================= final MLP =================
__global__ __launch_bounds__(256) void k_mlp(const unsigned* __restrict__ pooled,
                                             const float* __restrict__ fc1w, const float* __restrict__ fc1b,
                                             const float* __restrict__ fc2w, const float* __restrict__ fc2b,
                                             const float* __restrict__ cpdw, const float* __restrict__ cpdb,
                                             const float* __restrict__ combw, const float* __restrict__ combb,
                                             float* __restrict__ out, int G) {
    __shared__ float s1[64 * 32], s2[32 * 16], sb1[32], sb2[16], scw[16], sow[16], shead[2];
    int tid = threadIdx.x;
    for (int i = tid; i < 2048; i += 256) s1[i] = fc1w[i];
    for (int i = tid; i < 512; i += 256) s2[i] = fc2w[i];
    if (tid < 32) sb1[tid] = fc1b[tid];
    if (tid < 16) { sb2[tid] = fc2b[tid]; scw[tid] = cpdw[tid]; sow[tid] = combw[tid]; }
    if (tid == 0) { shead[0] = cpdb[0]; shead[1] = combb[0]; }
    __syncthreads();
    if (tid < G) {
        float h0[64];
#pragma unroll
        for (int k = 0; k < 64; ++k) {
            unsigned u = pooled[tid * 64 + k];
            unsigned b = (u & 0x80000000u) ? (u & 0x7fffffffu) : ~u;
            h0[k] = __uint_as_float(b);
        }
        float h1[32];
#pragma unroll
        for (int j = 0; j < 32; ++j) {
            float a = sb1[j];
#pragma unroll
            for (int k = 0; k < 64; ++k) a += h0[k] * s1[k * 32 + j];
            h1[j] = fmaxf(a, 0.f);
        }
        float h2[16];
#pragma unroll
        for (int j = 0; j < 16; ++j) {
            float a = sb2[j];
#pragma unroll
            for (int k = 0; k < 32; ++k) a += h1[k] * s2[k * 16 + j];
            h2[j] = fmaxf(a, 0.f);
        }
        float c1 = shead[0], c2 = shead[1];
#pragma unroll
        for (int k = 0; k < 16; ++k) { c1 += h2[k] * scw[k]; c2 += h2[k] * sow[k]; }
        out[tid] = c1;
        out[G + tid] = c2;
    }
}

extern "C" void kernel_launch(void* const* d_in, const int* in_sizes, int n_in,
                              void* d_out, int out_size, void* d_ws, size_t ws_size,
                              hipStream_t stream) {
    const float* x      = (const float*)d_in[0];
    const int*   ei     = (const int*)d_in[1];
    const int*   batch  = (const int*)d_in[2];
    const float* enc_w1 = (const float*)d_in[3];
    const float* enc_b1 = (const float*)d_in[4];
    const float* enc_w2 = (const float*)d_in[5];
    const float* enc_b2 = (const float*)d_in[6];
    const float* w1 = (const float*)d_in[7];   const float* b1 = (const float*)d_in[8];
    const float* w2 = (const float*)d_in[9];   const float* b2 = (const float*)d_in[10];
    const float* w3 = (const float*)d_in[11];  const float* b3 = (const float*)d_in[12];
    const float* sgw = (const float*)d_in[13]; const float* sgb = (const float*)d_in[14];
    const float* fc1w = (const float*)d_in[15]; const float* fc1b = (const float*)d_in[16];
    const float* fc2w = (const float*)d_in[17]; const float* fc2b = (const float*)d_in[18];
    const float* cpdw = (const float*)d_in[19]; const float* cpdb = (const float*)d_in[20];
    const float* combw = (const float*)d_in[21]; const float* combb = (const float*)d_in[22];

    const int n = in_sizes[0] / 128;
    const int E = in_sizes[1] / 2;
    const int G = out_size / 2;
    const int nb = (n + 511) >> 9;
    float* outp = (float*)d_out;

    char* p = (char*)d_ws;
    auto alloc = [&](size_t bytes) -> char* {
        char* r = p;
        p += (bytes + 255) & ~(size_t)255;
        return r;
    };
    int* rowptr      = (int*)alloc((size_t)(n + 1) * 4);
    float* dinv      = (float*)alloc((size_t)n * 4);
    int* bcnt        = (int*)alloc(256 * 4);
    int* bbase       = (int*)alloc(257 * 4);
    int* bcur        = (int*)alloc(256 * 4);
    int* colA        = (int*)alloc((size_t)E * 4);
    unsigned* pooled = (unsigned*)alloc((size_t)G * 64 * 4);
    __half* A        = (__half*)alloc((size_t)n * 128 * 4);  // oversized: aliases pairs (E*8 bytes)
    __half* B        = (__half*)alloc((size_t)n * 128 * 2);
    float* Cf        = (float*)alloc((size_t)n * 64 * 4);
    uint4* wcnt4     = (uint4*)alloc((size_t)n * 16);
    unsigned* bar    = (unsigned*)alloc(10 * 16 * 4);   // 10 layers x {8 counters + 8 flags}
    int2* pairs      = (int2*)A;  // alias: pairs dead before first k_mm writes A

    hipMemsetAsync(bcnt, 0, 256 * 4, stream);
    hipMemsetAsync(pooled, 0, (size_t)G * 64 * 4, stream);
    hipMemsetAsync(bar, 0, 10 * 16 * 4, stream);

    const int gE = (E + 4095) / 4096;
    k_bcount<<<gE, 256, 0, stream>>>(ei + E, bcnt, E);
    k_bscan<<<1, 256, 0, stream>>>(bcnt, bbase, bcur, rowptr, nb, n, E);
    k_bscatter<<<gE, 256, 0, stream>>>(ei, bcur, pairs, E);
    k_bfill<<<nb, 512, 0, stream>>>(pairs, bbase, rowptr, dinv, colA, wcnt4, n);

    const int gm128 = (n + 31) / 32;
    const int gm64  = (n + 63) / 64;
    const int gw    = (n + 195) / 196;             // 511 blocks @ 2/CU: fully resident
    const int nwin  = (n + (1 << WSHIFT) - 1) >> WSHIFT;

    // encoder layer 1: x fp32 -> A fp16 (two column halves), windowed propagate+relu
    k_mm<128, 64, true, false, float, __half><<<gm128, 256, 0, stream>>>(x, enc_w1, nullptr, dinv, A, n, 128, 128, 0);
    k_mm<128, 64, true, false, float, __half><<<gm128, 256, 0, stream>>>(x, enc_w1, nullptr, dinv, A, n, 128, 128, 64);
    k_wagg<0><<<gw, 256, 0, stream>>>(A, rowptr, wcnt4, colA, dinv, enc_b1, B, n, E, nwin, 16, 0, bar, 0);
    k_wagg<0><<<gw, 256, 0, stream>>>(A, rowptr, wcnt4, colA, dinv, enc_b1, B, n, E, nwin, 16, 8, bar, 1);
    // encoder layer 2: [N,128] fp16 -> [N,64] fp16
    k_mm<128, 64, true, false, __half, __half><<<gm128, 256, 0, stream>>>(B, enc_w2, nullptr, dinv, A, n, 64, 64, 0);
    k_wagg<1><<<gw, 256, 0, stream>>>(A, rowptr, wcnt4, colA, dinv, enc_b2, B, n, E, nwin, 8, 0, bar, 2);
    // conv1, conv2
    k_mm<64, 64, true, false, __half, __half><<<gm64, 256, 0, stream>>>(B, w1, nullptr, dinv, A, n, 64, 64, 0);
    k_wagg<0><<<gw, 256, 0, stream>>>(A, rowptr, wcnt4, colA, dinv, b1, B, n, E, nwin, 8, 0, bar, 3);
    k_mm<64, 64, true, false, __half, __half><<<gm64, 256, 0, stream>>>(B, w2, nullptr, dinv, A, n, 64, 64, 0);
    k_wagg<0><<<gw, 256, 0, stream>>>(A, rowptr, wcnt4, colA, dinv, b2, B, n, E, nwin, 8, 0, bar, 4);
    // conv3 (output pre-scaled by dinv for SG chain)
    k_mm<64, 64, true, false, __half, __half><<<gm64, 256, 0, stream>>>(B, w3, nullptr, dinv, A, n, 64, 64, 0);
    k_wagg<2><<<gw, 256, 0, stream>>>(A, rowptr, wcnt4, colA, dinv, b3, B, n, E, nwin, 8, 0, bar, 5);
    // SGConv K=4 propagates
    k_wagg<3><<<gw, 256, 0, stream>>>(B, rowptr, wcnt4, colA, dinv, b3, A, n, E, nwin, 8, 0, bar, 6);
    k_wagg<3><<<gw, 256, 0, stream>>>(A, rowptr, wcnt4, colA, dinv, b3, B, n, E, nwin, 8, 0, bar, 7);
    k_wagg<3><<<gw, 256, 0, stream>>>(B, rowptr, wcnt4, colA, dinv, b3, A, n, E, nwin, 8, 0, bar, 8);
    k_wagg<4><<<gw, 256, 0, stream>>>(A, rowptr, wcnt4, colA, dinv, b3, B, n, E, nwin, 8, 0, bar, 9);
    // SG linear -> fp32 for pool
    k_mm<64, 64, false, true, __half, float><<<gm64, 256, 0, stream>>>(B, sgw, sgb, dinv, Cf, n, 64, 64, 0);
    // pool + heads
    k_pool<<<(n + 127) / 128, 64, 0, stream>>>(Cf, batch, pooled, n);
    k_mlp<<<1, 256, 0, stream>>>(pooled, fc1w, fc1b, fc2w, fc2b, cpdw, cpdb, combw, combb, outp, G);
}

// Round 9
// 989.329 us; speedup vs baseline: 4.8919x; 4.7560x over previous
//
#include <hip/hip_runtime.h>
#include <hip/hip_fp16.h>
#include <cfloat>
#include <type_traits>

#define DEV __device__ __forceinline__

DEV unsigned enc_ord(float f) {
    unsigned u = __float_as_uint(f);
    return (u & 0x80000000u) ? ~u : (u | 0x80000000u);
}

// ================= bucketed CSR build =================
__global__ __launch_bounds__(256) void k_bcount(const int* __restrict__ dst, int* __restrict__ bcnt, int E) {
    __shared__ int hist[256];
    int tid = threadIdx.x;
    hist[tid] = 0;
    __syncthreads();
    int base = blockIdx.x * 4096;
#pragma unroll
    for (int j = 0; j < 16; ++j) {
        int e = base + j * 256 + tid;
        if (e < E) atomicAdd(&hist[dst[e] >> 9], 1);
    }
    __syncthreads();
    if (hist[tid]) atomicAdd(&bcnt[tid], hist[tid]);
}

__global__ __launch_bounds__(256) void k_bscan(const int* __restrict__ bcnt, int* __restrict__ bbase,
                                               int* __restrict__ bcur, int* __restrict__ rowptr,
                                               int nb, int n, int E) {
    __shared__ int sh[256];
    int tid = threadIdx.x;
    int v = (tid < nb) ? bcnt[tid] : 0;
    sh[tid] = v; __syncthreads();
    for (int off = 1; off < 256; off <<= 1) {
        int x = (tid >= off) ? sh[tid - off] : 0; __syncthreads();
        sh[tid] += x; __syncthreads();
    }
    int excl = sh[tid] - v;
    if (tid < nb) { bbase[tid] = excl; bcur[tid] = excl; }
    if (tid == 0) { bbase[nb] = E; rowptr[n] = E; }
}

__global__ __launch_bounds__(256) void k_bscatter(const int* __restrict__ ei, int* __restrict__ bcur,
                                                  int2* __restrict__ pairs, int E) {
    __shared__ int hist[256];
    __shared__ int gbase[256];
    int tid = threadIdx.x;
    hist[tid] = 0;
    __syncthreads();
    int base = blockIdx.x * 4096;
    int d[16], li[16];
#pragma unroll
    for (int j = 0; j < 16; ++j) {
        int e = base + j * 256 + tid;
        if (e < E) {
            d[j] = ei[E + e];
            li[j] = atomicAdd(&hist[d[j] >> 9], 1);
        }
    }
    __syncthreads();
    if (hist[tid]) gbase[tid] = atomicAdd(&bcur[tid], hist[tid]);
    __syncthreads();
#pragma unroll
    for (int j = 0; j < 16; ++j) {
        int e = base + j * 256 + tid;
        if (e < E) {
            int b = d[j] >> 9;
            pairs[gbase[b] + li[j]] = make_int2(ei[e], d[j]);
        }
    }
}

// Counting sort within each dst-bucket keyed by (dst_local, src>>13):
// per-row edge lists come out in ascending source windows (mild L2/L3 locality).
__global__ __launch_bounds__(512) void k_bfill(const int2* __restrict__ pairs, const int* __restrict__ bbase,
                                               int* __restrict__ rowptr, float* __restrict__ dinv,
                                               int* __restrict__ colA, int n) {
    constexpr int NW = 16;
    __shared__ int scnt[512 * NW];    // 32 KB
    __shared__ int sscan[512];
    int tid = threadIdx.x;
    int b = blockIdx.x;
    int bb = bbase[b], be = bbase[b + 1];
    int nodeBase = b << 9;
    for (int i = tid; i < 512 * NW; i += 512) scnt[i] = 0;
    __syncthreads();
    for (int e = bb + tid; e < be; e += 512) {
        int2 pr = pairs[e];
        atomicAdd(&scnt[(pr.y & 511) * NW + ((pr.x >> 13) & (NW - 1))], 1);
    }
    __syncthreads();
    int base = tid * NW;
    int cnt[NW];
    int deg = 0;
#pragma unroll
    for (int w = 0; w < NW; ++w) { cnt[w] = scnt[base + w]; deg += cnt[w]; }
    sscan[tid] = deg;
    __syncthreads();
    for (int off = 1; off < 512; off <<= 1) {
        int x = (tid >= off) ? sscan[tid - off] : 0; __syncthreads();
        sscan[tid] += x; __syncthreads();
    }
    int excl = sscan[tid] - deg;
    int node = nodeBase + tid;
    if (node < n) {
        rowptr[node] = bb + excl;
        dinv[node] = rsqrtf((float)deg + 1.0f);  // +1 self loop
    }
    int run = excl;
#pragma unroll
    for (int w = 0; w < NW; ++w) { int c = cnt[w]; scnt[base + w] = run; run += c; }
    __syncthreads();
    for (int e = bb + tid; e < be; e += 512) {
        int2 pr = pairs[e];
        int p = atomicAdd(&scnt[(pr.y & 511) * NW + ((pr.x >> 13) & (NW - 1))], 1);
        colA[bb + p] = pr.x;
    }
}

// ================= dense matmul =================
template <int K, int COUT, bool SCALE, bool BIAS, typename TIN, typename TOUT>
__global__ __launch_bounds__(256) void k_mm(const TIN* __restrict__ in, const float* __restrict__ W,
                                            const float* __restrict__ bias, const float* __restrict__ dinv,
                                            TOUT* __restrict__ out, int n, int ldw, int ldo, int colOff) {
    constexpr int CG = COUT / 4;
    constexpr int SLOTS = 256 / CG;
    constexpr int TR = (K == 128) ? 32 : 64;
    constexpr int RPT = TR / SLOTS;
    constexpr int KP = K + 1;
    __shared__ __align__(16) float sW[K * COUT];
    __shared__ float sH[TR * KP];
    const int tid = threadIdx.x;
    const int rowBase = blockIdx.x * TR;

    constexpr int W4 = COUT / 4;
    for (int idx = tid; idx < K * W4; idx += 256) {
        int k = idx / W4, c4 = idx - k * W4;
        ((float4*)sW)[idx] = *(const float4*)(W + (size_t)k * ldw + colOff + c4 * 4);
    }
    if constexpr (std::is_same<TIN, float>::value) {
        const float4* inp4 = (const float4*)(in + (size_t)rowBase * K);
        for (int idx = tid; idx < TR * K / 4; idx += 256) {
            int elem = idx * 4;
            int r = elem / K, k = elem - r * K;
            float4 h = (rowBase + r < n) ? inp4[idx] : make_float4(0.f, 0.f, 0.f, 0.f);
            float* dd = &sH[r * KP + k];
            dd[0] = h.x; dd[1] = h.y; dd[2] = h.z; dd[3] = h.w;
        }
    } else {
        const uint4* inp8 = (const uint4*)(in + (size_t)rowBase * K);
        for (int idx = tid; idx < TR * K / 8; idx += 256) {
            int elem = idx * 8;
            int r = elem / K, k = elem - r * K;
            uint4 h = make_uint4(0u, 0u, 0u, 0u);
            if (rowBase + r < n) h = inp8[idx];
            const __half2* hh = (const __half2*)&h;
            float* dd = &sH[r * KP + k];
#pragma unroll
            for (int q = 0; q < 4; ++q) {
                float2 f = __half22float2(hh[q]);
                dd[2 * q] = f.x; dd[2 * q + 1] = f.y;
            }
        }
    }
    __syncthreads();

    const int cg = tid % CG;
    const int slot = tid / CG;
    float4 acc[RPT];
#pragma unroll
    for (int j = 0; j < RPT; ++j) acc[j] = make_float4(0.f, 0.f, 0.f, 0.f);
#pragma unroll 4
    for (int k = 0; k < K; ++k) {
        float4 w = *(const float4*)&sW[k * COUT + cg * 4];
#pragma unroll
        for (int j = 0; j < RPT; ++j) {
            float h = sH[(slot + j * SLOTS) * KP + k];
            acc[j].x += h * w.x; acc[j].y += h * w.y; acc[j].z += h * w.z; acc[j].w += h * w.w;
        }
    }
#pragma unroll
    for (int j = 0; j < RPT; ++j) {
        int r = rowBase + slot + j * SLOTS;
        if (r < n) {
            float4 o = acc[j];
            if (SCALE) { float di = dinv[r]; o.x *= di; o.y *= di; o.z *= di; o.w *= di; }
            if (BIAS) {
                float4 b = *(const float4*)(bias + colOff + cg * 4);
                o.x += b.x; o.y += b.y; o.z += b.z; o.w += b.w;
            }
            if constexpr (std::is_same<TOUT, float>::value) {
                *(float4*)(out + (size_t)r * ldo + colOff + cg * 4) = o;
            } else {
                __half2 p0 = __floats2half2_rn(o.x, o.y);
                __half2 p1 = __floats2half2_rn(o.z, o.w);
                uint2 st;
                st.x = *(unsigned*)&p0; st.y = *(unsigned*)&p1;
                *(uint2*)(out + (size_t)r * ldo + colOff + cg * 4) = st;
            }
        }
    }
}

// ================= aggregation (pull, fp16 rows, DEPTH-deep pipelined gathers) ========
// s_i = g[i] + sum_{e in in(i)} g[col[e]]   (fp32 accumulate)
// MODE 0: out = relu(dinv*s + b)       MODE 1: out = dinv*s + b
// MODE 2: out = dinv*relu(dinv*s + b)  MODE 3: out = dinv^2*s   MODE 4: out = dinv*s
// DEPTH=12: 12 in-flight gathers per lane (r1's 8-deep at VGPR=44 left ~20 regs of
// headroom under the 64-VGPR occupancy cliff; +50% memory-level parallelism).
template <int WIDTH, int MODE, int DEPTH>
__global__ __launch_bounds__(256) void k_agg(const __half* __restrict__ g, const int* __restrict__ rowptr,
                                             const int* __restrict__ col, const float* __restrict__ dinv,
                                             const float* __restrict__ bias, __half* __restrict__ out, int n) {
    constexpr int LPR = WIDTH / 8;   // lanes per row (8 or 16): 16B of fp16 per lane
    constexpr int RPW = 64 / LPR;    // rows per wave (8 or 4)
    int gw = (blockIdx.x * 256 + threadIdx.x) >> 6;
    int lane = threadIdx.x & 63;
    int seg = lane / LPR;
    int sl = lane % LPR;
    int row = gw * RPW + seg;
    if (row >= n) return;
    const uint4* g4 = (const uint4*)g + sl;   // 16B units; row stride = LPR units
    float acc[8];
    {
        uint4 s = g4[(size_t)row * LPR];  // self loop
        const __half2* h = (const __half2*)&s;
#pragma unroll
        for (int q = 0; q < 4; ++q) {
            float2 f = __half22float2(h[q]);
            acc[2 * q] = f.x; acc[2 * q + 1] = f.y;
        }
    }
    int e0 = rowptr[row], e1 = rowptr[row + 1];
    if (e0 < e1) {
        const int e1m1 = e1 - 1;
        int c[DEPTH];
#pragma unroll
        for (int j = 0; j < DEPTH; ++j) c[j] = col[min(e0 + j, e1m1)];
        for (int eb = e0; eb < e1; eb += DEPTH) {
            uint4 v[DEPTH];
#pragma unroll
            for (int j = 0; j < DEPTH; ++j) v[j] = g4[(size_t)c[j] * LPR];
            int cn[DEPTH];
#pragma unroll
            for (int j = 0; j < DEPTH; ++j) cn[j] = col[min(eb + DEPTH + j, e1m1)];
            int rem = e1 - eb;
#pragma unroll
            for (int j = 0; j < DEPTH; ++j) {
                float m = (j < rem) ? 1.f : 0.f;
                const __half2* h = (const __half2*)&v[j];
#pragma unroll
                for (int q = 0; q < 4; ++q) {
                    float2 f = __half22float2(h[q]);
                    acc[2 * q]     = fmaf(m, f.x, acc[2 * q]);
                    acc[2 * q + 1] = fmaf(m, f.y, acc[2 * q + 1]);
                }
            }
#pragma unroll
            for (int j = 0; j < DEPTH; ++j) c[j] = cn[j];
        }
    }
    float di = dinv[row];
    float r8[8];
    if (MODE == 0 || MODE == 1 || MODE == 2) {
        float4 b0 = *(const float4*)(bias + sl * 8);
        float4 b1 = *(const float4*)(bias + sl * 8 + 4);
        float bb[8] = {b0.x, b0.y, b0.z, b0.w, b1.x, b1.y, b1.z, b1.w};
#pragma unroll
        for (int t = 0; t < 8; ++t) {
            float s = di * acc[t] + bb[t];
            if (MODE == 0) r8[t] = fmaxf(s, 0.f);
            else if (MODE == 1) r8[t] = s;
            else r8[t] = di * fmaxf(s, 0.f);
        }
    } else if (MODE == 3) {
        float d2 = di * di;
#pragma unroll
        for (int t = 0; t < 8; ++t) r8[t] = acc[t] * d2;
    } else {
#pragma unroll
        for (int t = 0; t < 8; ++t) r8[t] = acc[t] * di;
    }
    uint4 o;
    __half2* oh = (__half2*)&o;
#pragma unroll
    for (int q = 0; q < 4; ++q) oh[q] = __floats2half2_rn(r8[2 * q], r8[2 * q + 1]);
    *((uint4*)out + (size_t)row * LPR + sl) = o;
}

// ================= global max pool (batch sorted) =================
__global__ __launch_bounds__(64) void k_pool(const float* __restrict__ z, const int* __restrict__ batch,
                                             unsigned* __restrict__ pooled, int n) {
    constexpr int ROWS = 128;
    int lane = threadIdx.x;
    int r0 = blockIdx.x * ROWS;
    if (r0 >= n) return;
    int r1 = min(r0 + ROWS, n);
    int cur = batch[r0];
    float m = -FLT_MAX;
    for (int r = r0; r < r1; ++r) {
        int b = batch[r];
        float v = z[(size_t)r * 64 + lane];
        if (b != cur) {
            atomicMax(&pooled[cur * 64 + lane], enc_ord(m));
            cur = b; m = v;
        } else {
            m = fmaxf(m, v);
        }
    }
    atomicMax(&pooled[cur * 64 + lane], enc_ord(m));
}

// ================= final MLP =================
__global__ __launch_bounds__(256) void k_mlp(const unsigned* __restrict__ pooled,
                                             const float* __restrict__ fc1w, const float* __restrict__ fc1b,
                                             const float* __restrict__ fc2w, const float* __restrict__ fc2b,
                                             const float* __restrict__ cpdw, const float* __restrict__ cpdb,
                                             const float* __restrict__ combw, const float* __restrict__ combb,
                                             float* __restrict__ out, int G) {
    __shared__ float s1[64 * 32], s2[32 * 16], sb1[32], sb2[16], scw[16], sow[16], shead[2];
    int tid = threadIdx.x;
    for (int i = tid; i < 2048; i += 256) s1[i] = fc1w[i];
    for (int i = tid; i < 512; i += 256) s2[i] = fc2w[i];
    if (tid < 32) sb1[tid] = fc1b[tid];
    if (tid < 16) { sb2[tid] = fc2b[tid]; scw[tid] = cpdw[tid]; sow[tid] = combw[tid]; }
    if (tid == 0) { shead[0] = cpdb[0]; shead[1] = combb[0]; }
    __syncthreads();
    if (tid < G) {
        float h0[64];
#pragma unroll
        for (int k = 0; k < 64; ++k) {
            unsigned u = pooled[tid * 64 + k];
            unsigned b = (u & 0x80000000u) ? (u & 0x7fffffffu) : ~u;
            h0[k] = __uint_as_float(b);
        }
        float h1[32];
#pragma unroll
        for (int j = 0; j < 32; ++j) {
            float a = sb1[j];
#pragma unroll
            for (int k = 0; k < 64; ++k) a += h0[k] * s1[k * 32 + j];
            h1[j] = fmaxf(a, 0.f);
        }
        float h2[16];
#pragma unroll
        for (int j = 0; j < 16; ++j) {
            float a = sb2[j];
#pragma unroll
            for (int k = 0; k < 32; ++k) a += h1[k] * s2[k * 16 + j];
            h2[j] = fmaxf(a, 0.f);
        }
        float c1 = shead[0], c2 = shead[1];
#pragma unroll
        for (int k = 0; k < 16; ++k) { c1 += h2[k] * scw[k]; c2 += h2[k] * sow[k]; }
        out[tid] = c1;
        out[G + tid] = c2;
    }
}

extern "C" void kernel_launch(void* const* d_in, const int* in_sizes, int n_in,
                              void* d_out, int out_size, void* d_ws, size_t ws_size,
                              hipStream_t stream) {
    const float* x      = (const float*)d_in[0];
    const int*   ei     = (const int*)d_in[1];
    const int*   batch  = (const int*)d_in[2];
    const float* enc_w1 = (const float*)d_in[3];
    const float* enc_b1 = (const float*)d_in[4];
    const float* enc_w2 = (const float*)d_in[5];
    const float* enc_b2 = (const float*)d_in[6];
    const float* w1 = (const float*)d_in[7];   const float* b1 = (const float*)d_in[8];
    const float* w2 = (const float*)d_in[9];   const float* b2 = (const float*)d_in[10];
    const float* w3 = (const float*)d_in[11];  const float* b3 = (const float*)d_in[12];
    const float* sgw = (const float*)d_in[13]; const float* sgb = (const float*)d_in[14];
    const float* fc1w = (const float*)d_in[15]; const float* fc1b = (const float*)d_in[16];
    const float* fc2w = (const float*)d_in[17]; const float* fc2b = (const float*)d_in[18];
    const float* cpdw = (const float*)d_in[19]; const float* cpdb = (const float*)d_in[20];
    const float* combw = (const float*)d_in[21]; const float* combb = (const float*)d_in[22];

    const int n = in_sizes[0] / 128;
    const int E = in_sizes[1] / 2;
    const int G = out_size / 2;
    const int nb = (n + 511) >> 9;
    float* outp = (float*)d_out;

    char* p = (char*)d_ws;
    auto alloc = [&](size_t bytes) -> char* {
        char* r = p;
        p += (bytes + 255) & ~(size_t)255;
        return r;
    };
    int* rowptr      = (int*)alloc((size_t)(n + 1) * 4);
    float* dinv      = (float*)alloc((size_t)n * 4);
    int* bcnt        = (int*)alloc(256 * 4);
    int* bbase       = (int*)alloc(257 * 4);
    int* bcur        = (int*)alloc(256 * 4);
    int* colA        = (int*)alloc((size_t)E * 4);
    unsigned* pooled = (unsigned*)alloc((size_t)G * 64 * 4);
    __half* A        = (__half*)alloc((size_t)n * 128 * 4);  // oversized: aliases pairs (E*8 bytes)
    __half* B        = (__half*)alloc((size_t)n * 128 * 2);
    float* Cf        = (float*)alloc((size_t)n * 64 * 4);
    int2* pairs      = (int2*)A;  // alias: pairs dead before first k_mm writes A

    hipMemsetAsync(bcnt, 0, 256 * 4, stream);
    hipMemsetAsync(pooled, 0, (size_t)G * 64 * 4, stream);

    const int gE = (E + 4095) / 4096;
    k_bcount<<<gE, 256, 0, stream>>>(ei + E, bcnt, E);
    k_bscan<<<1, 256, 0, stream>>>(bcnt, bbase, bcur, rowptr, nb, n, E);
    k_bscatter<<<gE, 256, 0, stream>>>(ei, bcur, pairs, E);
    k_bfill<<<nb, 512, 0, stream>>>(pairs, bbase, rowptr, dinv, colA, n);

    const int gm128 = (n + 31) / 32;
    const int gm64  = (n + 63) / 64;
    const int ga64  = (n + 31) / 32;   // 8 rows/wave, 4 waves/block
    const int ga128 = (n + 15) / 16;   // 4 rows/wave

    // encoder layer 1: x fp32 -> A fp16 (two column halves), propagate+relu
    k_mm<128, 64, true, false, float, __half><<<gm128, 256, 0, stream>>>(x, enc_w1, nullptr, dinv, A, n, 128, 128, 0);
    k_mm<128, 64, true, false, float, __half><<<gm128, 256, 0, stream>>>(x, enc_w1, nullptr, dinv, A, n, 128, 128, 64);
    k_agg<128, 0, 12><<<ga128, 256, 0, stream>>>(A, rowptr, colA, dinv, enc_b1, B, n);
    // encoder layer 2: [N,128] fp16 -> [N,64] fp16
    k_mm<128, 64, true, false, __half, __half><<<gm128, 256, 0, stream>>>(B, enc_w2, nullptr, dinv, A, n, 64, 64, 0);
    k_agg<64, 1, 12><<<ga64, 256, 0, stream>>>(A, rowptr, colA, dinv, enc_b2, B, n);
    // conv1, conv2
    k_mm<64, 64, true, false, __half, __half><<<gm64, 256, 0, stream>>>(B, w1, nullptr, dinv, A, n, 64, 64, 0);
    k_agg<64, 0, 12><<<ga64, 256, 0, stream>>>(A, rowptr, colA, dinv, b1, B, n);
    k_mm<64, 64, true, false, __half, __half><<<gm64, 256, 0, stream>>>(B, w2, nullptr, dinv, A, n, 64, 64, 0);
    k_agg<64, 0, 12><<<ga64, 256, 0, stream>>>(A, rowptr, colA, dinv, b2, B, n);
    // conv3 (output pre-scaled by dinv for SG chain)
    k_mm<64, 64, true, false, __half, __half><<<gm64, 256, 0, stream>>>(B, w3, nullptr, dinv, A, n, 64, 64, 0);
    k_agg<64, 2, 12><<<ga64, 256, 0, stream>>>(A, rowptr, colA, dinv, b3, B, n);
    // SGConv K=4 propagates
    k_agg<64, 3, 12><<<ga64, 256, 0, stream>>>(B, rowptr, colA, dinv, b3, A, n);
    k_agg<64, 3, 12><<<ga64, 256, 0, stream>>>(A, rowptr, colA, dinv, b3, B, n);
    k_agg<64, 3, 12><<<ga64, 256, 0, stream>>>(B, rowptr, colA, dinv, b3, A, n);
    k_agg<64, 4, 12><<<ga64, 256, 0, stream>>>(A, rowptr, colA, dinv, b3, B, n);
    // SG linear -> fp32 for pool
    k_mm<64, 64, false, true, __half, float><<<gm64, 256, 0, stream>>>(B, sgw, sgb, dinv, Cf, n, 64, 64, 0);
    // pool + heads
    k_pool<<<(n + 127) / 128, 64, 0, stream>>>(Cf, batch, pooled, n);
    k_mlp<<<1, 256, 0, stream>>>(pooled, fc1w, fc1b, fc2w, fc2b, cpdw, cpdb, combw, combb, outp, G);
}